// Round 5
// baseline (5145.721 us; speedup 1.0000x reference)
//
#include <hip/hip_runtime.h>
#include <hip/hip_bf16.h>

#define NNODES 8192
#define NEDGES 262144
#define HDIM 128
#define NLAYERS 6
#define NMASK (NNODES - 1)

__device__ __forceinline__ float silu_f(float x) { return x / (1.0f + __expf(-x)); }

// ---------------------------------------------------------------- probes
// flags[1] = 1 if edge_index is int64 (high words of first 4 entries all 0)
__global__ void detect_kernel(const int* __restrict__ ei32, int* __restrict__ flags) {
    if (blockIdx.x == 0 && threadIdx.x == 0) {
        flags[1] = (ei32[1] == 0 && ei32[3] == 0 && ei32[5] == 0 && ei32[7] == 0) ? 1 : 0;
    }
}

__device__ __forceinline__ int load_idx(const void* ei, int is64, int i) {
    int v = is64 ? (int)(((const long long*)ei)[i]) : ((const int*)ei)[i];
    return v & NMASK;
}

// ---------------------------------------------------------------- pos init (fp32 copy into d_out)
__global__ void pos_init_kernel(const float* __restrict__ pin, float* __restrict__ pos) {
    int i = blockIdx.x * blockDim.x + threadIdx.x;
    if (i < NNODES * 3) pos[i] = pin[i];
}

// ---------------------------------------------------------------- degree
__global__ void deg_kernel(const void* __restrict__ ei, const int* __restrict__ flags,
                           float* __restrict__ deg) {
    int i = blockIdx.x * blockDim.x + threadIdx.x;
    if (i < NEDGES) {
        int r = load_idx(ei, flags[1], i);
        atomicAdd(&deg[r], 1.0f);
    }
}

// ---------------------------------------------------------------- injection MLP
// 16 nodes per block, 256 threads. LDS ~30.5 KB.
__global__ __launch_bounds__(256) void inj_kernel(
    const float* __restrict__ atom, const float* __restrict__ z,
    const float* __restrict__ W1, const float* __restrict__ b1,
    const float* __restrict__ W2, const float* __restrict__ b2,
    const float* __restrict__ W3, const float* __restrict__ b3,
    float* __restrict__ h)
{
    __shared__ __align__(16) float in_s[16][84];   // 80 used
    __shared__ __align__(16) float s1[16][260];    // 256 used
    __shared__ __align__(16) float s2[16][132];    // 128 used
    const int tid = threadIdx.x;
    const int n0 = blockIdx.x * 16;

    if (tid < 80) {
        for (int e = 0; e < 16; ++e) {
            int n = n0 + e;
            in_s[e][tid] = (tid < 16) ? atom[n * 16 + tid]
                                      : z[(n >> 5) * 64 + (tid - 16)];
        }
    }
    __syncthreads();

    // layer1: 80 -> 256, thread = output channel
    {
        float acc[16];
        float bias = b1[tid];
#pragma unroll
        for (int e = 0; e < 16; ++e) acc[e] = bias;
        for (int k4 = 0; k4 < 20; ++k4) {
            float w0 = W1[(k4 * 4 + 0) * 256 + tid];
            float w1 = W1[(k4 * 4 + 1) * 256 + tid];
            float w2 = W1[(k4 * 4 + 2) * 256 + tid];
            float w3 = W1[(k4 * 4 + 3) * 256 + tid];
#pragma unroll
            for (int e = 0; e < 16; ++e) {
                const float4 v = *(const float4*)&in_s[e][k4 * 4];
                acc[e] += v.x * w0 + v.y * w1 + v.z * w2 + v.w * w3;
            }
        }
#pragma unroll
        for (int e = 0; e < 16; ++e) s1[e][tid] = silu_f(acc[e]);
    }
    __syncthreads();

    const int j = tid & 127, hv = tid >> 7;
    // layer2: 256 -> 128
    {
        float acc[8];
        float bias = b2[j];
#pragma unroll
        for (int e = 0; e < 8; ++e) acc[e] = bias;
        for (int k4 = 0; k4 < 64; ++k4) {
            float w0 = W2[(k4 * 4 + 0) * 128 + j];
            float w1 = W2[(k4 * 4 + 1) * 128 + j];
            float w2 = W2[(k4 * 4 + 2) * 128 + j];
            float w3 = W2[(k4 * 4 + 3) * 128 + j];
#pragma unroll
            for (int e = 0; e < 8; ++e) {
                const float4 v = *(const float4*)&s1[hv * 8 + e][k4 * 4];
                acc[e] += v.x * w0 + v.y * w1 + v.z * w2 + v.w * w3;
            }
        }
#pragma unroll
        for (int e = 0; e < 8; ++e) s2[hv * 8 + e][j] = silu_f(acc[e]);
    }
    __syncthreads();

    // layer3: 128 -> 128, no activation
    {
        float acc[8];
        float bias = b3[j];
#pragma unroll
        for (int e = 0; e < 8; ++e) acc[e] = bias;
        for (int k4 = 0; k4 < 32; ++k4) {
            float w0 = W3[(k4 * 4 + 0) * 128 + j];
            float w1 = W3[(k4 * 4 + 1) * 128 + j];
            float w2 = W3[(k4 * 4 + 2) * 128 + j];
            float w3 = W3[(k4 * 4 + 3) * 128 + j];
#pragma unroll
            for (int e = 0; e < 8; ++e) {
                const float4 v = *(const float4*)&s2[hv * 8 + e][k4 * 4];
                acc[e] += v.x * w0 + v.y * w1 + v.z * w2 + v.w * w3;
            }
        }
#pragma unroll
        for (int e = 0; e < 8; ++e) h[(n0 + hv * 8 + e) * HDIM + j] = acc[e];
    }
}

// ---------------------------------------------------------------- edge MLP + scatter
// 16 edges per block, 256 threads. LDS ~33.9 KB.
__global__ __launch_bounds__(256) void edge_kernel(
    const float* __restrict__ h, const float* __restrict__ pos,
    const void* __restrict__ ei, const int* __restrict__ flags,
    const float* __restrict__ W1, const float* __restrict__ b1,
    const float* __restrict__ W2, const float* __restrict__ b2,
    const float* __restrict__ cW1, const float* __restrict__ cb1,
    const float* __restrict__ cW2,
    float* __restrict__ agg, float* __restrict__ cu)
{
    __shared__ __align__(16) float ef[16][260];   // [h_row | h_col | dist_sq]
    __shared__ __align__(16) float h1[16][132];
    __shared__ __align__(16) float mm[16][132];
    __shared__ int row_s[16], col_s[16];
    __shared__ float dps[16][3];

    const int tid = threadIdx.x;
    const int e0 = blockIdx.x * 16;

    if (tid < 16) {
        const int is64 = flags[1];
        int r = load_idx(ei, is64, e0 + tid);
        int c = load_idx(ei, is64, NEDGES + e0 + tid);
        row_s[tid] = r; col_s[tid] = c;
        float dx = pos[r * 3 + 0] - pos[c * 3 + 0];
        float dy = pos[r * 3 + 1] - pos[c * 3 + 1];
        float dz = pos[r * 3 + 2] - pos[c * 3 + 2];
        dps[tid][0] = dx; dps[tid][1] = dy; dps[tid][2] = dz;
        ef[tid][256] = dx * dx + dy * dy + dz * dz;
    }
    __syncthreads();

    const int j = tid & 127, hv = tid >> 7;
    {
        const int off = hv * 128;
        for (int e = 0; e < 16; ++e) {
            int n = hv ? col_s[e] : row_s[e];
            ef[e][off + j] = h[n * HDIM + j];
        }
    }
    __syncthreads();

    float acc[8];
    // layer1: 257 -> 128
    {
        float bias = b1[j];
#pragma unroll
        for (int e = 0; e < 8; ++e) acc[e] = bias;
        for (int k4 = 0; k4 < 64; ++k4) {
            float w0 = W1[(k4 * 4 + 0) * 128 + j];
            float w1 = W1[(k4 * 4 + 1) * 128 + j];
            float w2 = W1[(k4 * 4 + 2) * 128 + j];
            float w3 = W1[(k4 * 4 + 3) * 128 + j];
#pragma unroll
            for (int e = 0; e < 8; ++e) {
                const float4 v = *(const float4*)&ef[hv * 8 + e][k4 * 4];
                acc[e] += v.x * w0 + v.y * w1 + v.z * w2 + v.w * w3;
            }
        }
        float w256 = W1[256 * 128 + j];
#pragma unroll
        for (int e = 0; e < 8; ++e) acc[e] += ef[hv * 8 + e][256] * w256;
#pragma unroll
        for (int e = 0; e < 8; ++e) h1[hv * 8 + e][j] = silu_f(acc[e]);
    }
    __syncthreads();

    // layer2: 128 -> 128 => m
    {
        float bias = b2[j];
#pragma unroll
        for (int e = 0; e < 8; ++e) acc[e] = bias;
        for (int k4 = 0; k4 < 32; ++k4) {
            float w0 = W2[(k4 * 4 + 0) * 128 + j];
            float w1 = W2[(k4 * 4 + 1) * 128 + j];
            float w2 = W2[(k4 * 4 + 2) * 128 + j];
            float w3 = W2[(k4 * 4 + 3) * 128 + j];
#pragma unroll
            for (int e = 0; e < 8; ++e) {
                const float4 v = *(const float4*)&h1[hv * 8 + e][k4 * 4];
                acc[e] += v.x * w0 + v.y * w1 + v.z * w2 + v.w * w3;
            }
        }
#pragma unroll
        for (int e = 0; e < 8; ++e) mm[hv * 8 + e][j] = silu_f(acc[e]);
    }
    __syncthreads();

    // coord head: c1 = silu(m @ cW1 + cb1); h1 := c1 * cW2[j]
    {
        float bias = cb1[j];
#pragma unroll
        for (int e = 0; e < 8; ++e) acc[e] = bias;
        for (int k4 = 0; k4 < 32; ++k4) {
            float w0 = cW1[(k4 * 4 + 0) * 128 + j];
            float w1 = cW1[(k4 * 4 + 1) * 128 + j];
            float w2 = cW1[(k4 * 4 + 2) * 128 + j];
            float w3 = cW1[(k4 * 4 + 3) * 128 + j];
#pragma unroll
            for (int e = 0; e < 8; ++e) {
                const float4 v = *(const float4*)&mm[hv * 8 + e][k4 * 4];
                acc[e] += v.x * w0 + v.y * w1 + v.z * w2 + v.w * w3;
            }
        }
        float cwj = cW2[j];
#pragma unroll
        for (int e = 0; e < 8; ++e) h1[hv * 8 + e][j] = silu_f(acc[e]) * cwj;
    }
    __syncthreads();

    // cw reduce + coord scatter (threads 0..15, one edge each)
    if (tid < 16) {
        float s = 0.0f;
#pragma unroll
        for (int k4 = 0; k4 < 32; ++k4) {
            const float4 v = *(const float4*)&h1[tid][k4 * 4];
            s += v.x + v.y + v.z + v.w;
        }
        int r = row_s[tid];
        atomicAdd(&cu[r * 3 + 0], s * dps[tid][0]);
        atomicAdd(&cu[r * 3 + 1], s * dps[tid][1]);
        atomicAdd(&cu[r * 3 + 2], s * dps[tid][2]);
    }
    // agg scatter
#pragma unroll
    for (int e = 0; e < 8; ++e) {
        int ee = hv * 8 + e;
        atomicAdd(&agg[row_s[ee] * HDIM + j], mm[ee][j]);
    }
}

// ---------------------------------------------------------------- node MLP + LN + pos
// 16 nodes per block, 256 threads. h2 may ALIAS agg (own rows only).
__global__ __launch_bounds__(256) void node_kernel(
    const float* __restrict__ h, const float* __restrict__ agg,
    const float* __restrict__ cu, const float* __restrict__ deg,
    const float* __restrict__ W1, const float* __restrict__ b1,
    const float* __restrict__ W2, const float* __restrict__ b2,
    const float* __restrict__ lg, const float* __restrict__ lb,
    float* __restrict__ h2, float* __restrict__ pos)
{
    __shared__ __align__(16) float xin[16][260];  // [h || agg]
    __shared__ __align__(16) float s1[16][132];
    __shared__ __align__(16) float xv[16][132];   // h + nu
    __shared__ float mus[16], rss[16];

    const int tid = threadIdx.x;
    const int n0 = blockIdx.x * 16;
    const int j = tid & 127, hv = tid >> 7;

    {
        const int off = hv * 128;
        for (int e = 0; e < 16; ++e) {
            int n = n0 + e;
            xin[e][off + j] = hv ? agg[n * HDIM + j] : h[n * HDIM + j];
        }
    }
    __syncthreads();

    float acc[8];
    // layer1: 256 -> 128
    {
        float bias = b1[j];
#pragma unroll
        for (int e = 0; e < 8; ++e) acc[e] = bias;
        for (int k4 = 0; k4 < 64; ++k4) {
            float w0 = W1[(k4 * 4 + 0) * 128 + j];
            float w1 = W1[(k4 * 4 + 1) * 128 + j];
            float w2 = W1[(k4 * 4 + 2) * 128 + j];
            float w3 = W1[(k4 * 4 + 3) * 128 + j];
#pragma unroll
            for (int e = 0; e < 8; ++e) {
                const float4 v = *(const float4*)&xin[hv * 8 + e][k4 * 4];
                acc[e] += v.x * w0 + v.y * w1 + v.z * w2 + v.w * w3;
            }
        }
#pragma unroll
        for (int e = 0; e < 8; ++e) s1[hv * 8 + e][j] = silu_f(acc[e]);
    }
    __syncthreads();

    // layer2: 128 -> 128 => nu; x = h + nu
    {
        float bias = b2[j];
#pragma unroll
        for (int e = 0; e < 8; ++e) acc[e] = bias;
        for (int k4 = 0; k4 < 32; ++k4) {
            float w0 = W2[(k4 * 4 + 0) * 128 + j];
            float w1 = W2[(k4 * 4 + 1) * 128 + j];
            float w2 = W2[(k4 * 4 + 2) * 128 + j];
            float w3 = W2[(k4 * 4 + 3) * 128 + j];
#pragma unroll
            for (int e = 0; e < 8; ++e) {
                const float4 v = *(const float4*)&s1[hv * 8 + e][k4 * 4];
                acc[e] += v.x * w0 + v.y * w1 + v.z * w2 + v.w * w3;
            }
        }
#pragma unroll
        for (int e = 0; e < 8; ++e) {
            int ee = hv * 8 + e;
            xv[ee][j] = xin[ee][j] + acc[e];
        }
    }
    __syncthreads();

    // LN stats + pos update (threads 0..15)
    if (tid < 16) {
        float s = 0.0f, ss = 0.0f;
#pragma unroll
        for (int k4 = 0; k4 < 32; ++k4) {
            const float4 v = *(const float4*)&xv[tid][k4 * 4];
            s  += v.x + v.y + v.z + v.w;
            ss += v.x * v.x + v.y * v.y + v.z * v.z + v.w * v.w;
        }
        float mu = s * (1.0f / 128.0f);
        float var = ss * (1.0f / 128.0f) - mu * mu;
        mus[tid] = mu;
        rss[tid] = rsqrtf(fmaxf(var, 0.0f) + 1e-5f);
        int n = n0 + tid;
        float inv = 1.0f / (deg[n] + 1e-6f);
        pos[n * 3 + 0] += cu[n * 3 + 0] * inv;
        pos[n * 3 + 1] += cu[n * 3 + 1] * inv;
        pos[n * 3 + 2] += cu[n * 3 + 2] * inv;
    }
    __syncthreads();

    // h2 = LN(x)*g + b
    {
        float gg = lg[j], bb = lb[j];
#pragma unroll
        for (int e = 0; e < 8; ++e) {
            int ee = hv * 8 + e;
            h2[(n0 + ee) * HDIM + j] = (xv[ee][j] - mus[ee]) * rss[ee] * gg + bb;
        }
    }
}

// ---------------------------------------------------------------- launch
extern "C" void kernel_launch(void* const* d_in, const int* in_sizes, int n_in,
                              void* d_out, int out_size, void* d_ws, size_t ws_size,
                              hipStream_t stream) {
    // setup_inputs() dict order, all floats fp32 (established R1 vs R2 A/B):
    const float* zF    = (const float*)d_in[0];
    const float* atomF = (const float*)d_in[1];
    const float* posI  = (const float*)d_in[2];
    const void*  ei    = d_in[3];
    const float* iW1 = (const float*)d_in[5];  const float* ib1 = (const float*)d_in[6];
    const float* iW2 = (const float*)d_in[7];  const float* ib2 = (const float*)d_in[8];
    const float* iW3 = (const float*)d_in[9];  const float* ib3 = (const float*)d_in[10];
    const float* eW1 = (const float*)d_in[11]; const float* eb1 = (const float*)d_in[12];
    const float* eW2 = (const float*)d_in[13]; const float* eb2 = (const float*)d_in[14];
    const float* nW1 = (const float*)d_in[15]; const float* nb1 = (const float*)d_in[16];
    const float* nW2 = (const float*)d_in[17]; const float* nb2 = (const float*)d_in[18];
    const float* cW1 = (const float*)d_in[19]; const float* cb1 = (const float*)d_in[20];
    const float* cW2 = (const float*)d_in[21];
    const float* lng = (const float*)d_in[22]; const float* lnb = (const float*)d_in[23];

    // OUTPUT IS FP32: pos lives directly in d_out. (R0 zero-output error =
    // 0.40625 = absmax(ref); R2-4 bf16-packed writes read as fp32 gave the
    // decorrelated-pairs signature 0.5596.)
    float* pos = (float*)d_out;

    float* ws = (float*)d_ws;
    int* flags = (int*)d_ws;
    size_t cur = 16;
    auto carve = [&](size_t n) { float* p = ws + cur; cur += n; return p; };
    float* deg  = carve(NNODES);
    float* cu   = carve((size_t)NNODES * 3);
    float* bufA = carve((size_t)NNODES * HDIM);   // h
    float* bufB = carve((size_t)NNODES * HDIM);   // agg / h2 (aliased)

    detect_kernel<<<1, 64, 0, stream>>>((const int*)ei, flags);
    pos_init_kernel<<<(NNODES * 3 + 255) / 256, 256, 0, stream>>>(posI, pos);
    hipMemsetAsync(deg, 0, NNODES * sizeof(float), stream);
    deg_kernel<<<NEDGES / 256, 256, 0, stream>>>(ei, flags, deg);

    inj_kernel<<<NNODES / 16, 256, 0, stream>>>(atomF, zF, iW1, ib1, iW2, ib2, iW3, ib3, bufA);

    float* h = bufA;
    float* o = bufB;
    for (int l = 0; l < NLAYERS; ++l) {
        hipMemsetAsync(o, 0, (size_t)NNODES * HDIM * sizeof(float), stream);
        hipMemsetAsync(cu, 0, (size_t)NNODES * 3 * sizeof(float), stream);
        edge_kernel<<<NEDGES / 16, 256, 0, stream>>>(
            h, pos, ei, flags,
            eW1 + (size_t)l * 257 * 128, eb1 + l * 128,
            eW2 + (size_t)l * 128 * 128, eb2 + l * 128,
            cW1 + (size_t)l * 128 * 128, cb1 + l * 128,
            cW2 + l * 128, o, cu);
        node_kernel<<<NNODES / 16, 256, 0, stream>>>(
            h, o, cu, deg,
            nW1 + (size_t)l * 256 * 128, nb1 + l * 128,
            nW2 + (size_t)l * 128 * 128, nb2 + l * 128,
            lng + l * 128, lnb + l * 128, /*h2=*/o, pos);
        float* t = h; h = o; o = t;
    }
    // final pos already in d_out (fp32)
}

// Round 6
// 1797.240 us; speedup vs baseline: 2.8631x; 2.8631x over previous
//
#include <hip/hip_runtime.h>
#include <hip/hip_bf16.h>

#define NNODES 8192
#define NEDGES 262144
#define HDIM 128
#define NLAYERS 6
#define NMASK (NNODES - 1)

typedef __attribute__((ext_vector_type(8))) short bf16x8;   // 8 bf16 = 4 VGPR
typedef __attribute__((ext_vector_type(4))) float f32x4;    // MFMA acc

__device__ __forceinline__ float silu_f(float x) { return x / (1.0f + __expf(-x)); }
__device__ __forceinline__ unsigned short f2bu(float x) {
    __hip_bfloat16 h = __float2bfloat16(x);
    unsigned short u; __builtin_memcpy(&u, &h, 2); return u;
}
__device__ __forceinline__ float bu2f(unsigned short u) {
    __hip_bfloat16 h; __builtin_memcpy(&h, &u, 2); return __bfloat162float(h);
}

// ---------------------------------------------------------------- probes
__global__ void detect_kernel(const int* __restrict__ ei32, int* __restrict__ flags) {
    if (blockIdx.x == 0 && threadIdx.x == 0) {
        flags[1] = (ei32[1] == 0 && ei32[3] == 0 && ei32[5] == 0 && ei32[7] == 0) ? 1 : 0;
    }
}
__device__ __forceinline__ int load_idx(const void* ei, int is64, int i) {
    int v = is64 ? (int)(((const long long*)ei)[i]) : ((const int*)ei)[i];
    return v & NMASK;
}

// ---------------------------------------------------------------- pos init / degree
__global__ void pos_init_kernel(const float* __restrict__ pin, float* __restrict__ pos) {
    int i = blockIdx.x * blockDim.x + threadIdx.x;
    if (i < NNODES * 3) pos[i] = pin[i];
}
__global__ void deg_kernel(const void* __restrict__ ei, const int* __restrict__ flags,
                           float* __restrict__ deg) {
    int i = blockIdx.x * blockDim.x + threadIdx.x;
    if (i < NEDGES) atomicAdd(&deg[load_idx(ei, flags[1], i)], 1.0f);
}

// ---------------------------------------------------------------- weight prep
// w1t: [L][128 n][264 k] bf16 (k<257 valid, rest 0); w2t/c1t: [L][128 n][136 k]
__global__ void prep_weights_kernel(const float* __restrict__ eW1,
                                    const float* __restrict__ eW2,
                                    const float* __restrict__ cW1,
                                    unsigned short* __restrict__ w1t,
                                    unsigned short* __restrict__ w2t,
                                    unsigned short* __restrict__ c1t) {
    const int T1 = NLAYERS * 128 * 264;
    const int T2 = NLAYERS * 128 * 136;
    for (int i = blockIdx.x * blockDim.x + threadIdx.x; i < T1 + 2 * T2;
         i += gridDim.x * blockDim.x) {
        if (i < T1) {
            int l = i / (128 * 264), r = i % (128 * 264), n = r / 264, k = r % 264;
            float v = (k < 257) ? eW1[((size_t)l * 257 + k) * 128 + n] : 0.0f;
            w1t[i] = f2bu(v);
        } else {
            int ii = i - T1, which = ii / T2, r = ii % T2;
            int l = r / (128 * 136), rr = r % (128 * 136), n = rr / 136, k = rr % 136;
            const float* W = which ? cW1 : eW2;
            unsigned short* O = which ? c1t : w2t;
            float v = (k < 128) ? W[((size_t)l * 128 + k) * 128 + n] : 0.0f;
            O[r] = f2bu(v);
        }
    }
}

// ---------------------------------------------------------------- injection MLP (fp32, + bf16 copy of h)
__global__ __launch_bounds__(256) void inj_kernel(
    const float* __restrict__ atom, const float* __restrict__ z,
    const float* __restrict__ W1, const float* __restrict__ b1,
    const float* __restrict__ W2, const float* __restrict__ b2,
    const float* __restrict__ W3, const float* __restrict__ b3,
    float* __restrict__ h, unsigned short* __restrict__ hb)
{
    __shared__ __align__(16) float in_s[16][84];
    __shared__ __align__(16) float s1[16][260];
    __shared__ __align__(16) float s2[16][132];
    const int tid = threadIdx.x;
    const int n0 = blockIdx.x * 16;

    if (tid < 80) {
        for (int e = 0; e < 16; ++e) {
            int n = n0 + e;
            in_s[e][tid] = (tid < 16) ? atom[n * 16 + tid] : z[(n >> 5) * 64 + (tid - 16)];
        }
    }
    __syncthreads();
    {
        float acc[16];
        float bias = b1[tid];
#pragma unroll
        for (int e = 0; e < 16; ++e) acc[e] = bias;
        for (int k4 = 0; k4 < 20; ++k4) {
            float w0 = W1[(k4 * 4 + 0) * 256 + tid];
            float w1 = W1[(k4 * 4 + 1) * 256 + tid];
            float w2 = W1[(k4 * 4 + 2) * 256 + tid];
            float w3 = W1[(k4 * 4 + 3) * 256 + tid];
#pragma unroll
            for (int e = 0; e < 16; ++e) {
                const float4 v = *(const float4*)&in_s[e][k4 * 4];
                acc[e] += v.x * w0 + v.y * w1 + v.z * w2 + v.w * w3;
            }
        }
#pragma unroll
        for (int e = 0; e < 16; ++e) s1[e][tid] = silu_f(acc[e]);
    }
    __syncthreads();
    const int j = tid & 127, hv = tid >> 7;
    {
        float acc[8];
        float bias = b2[j];
#pragma unroll
        for (int e = 0; e < 8; ++e) acc[e] = bias;
        for (int k4 = 0; k4 < 64; ++k4) {
            float w0 = W2[(k4 * 4 + 0) * 128 + j];
            float w1 = W2[(k4 * 4 + 1) * 128 + j];
            float w2 = W2[(k4 * 4 + 2) * 128 + j];
            float w3 = W2[(k4 * 4 + 3) * 128 + j];
#pragma unroll
            for (int e = 0; e < 8; ++e) {
                const float4 v = *(const float4*)&s1[hv * 8 + e][k4 * 4];
                acc[e] += v.x * w0 + v.y * w1 + v.z * w2 + v.w * w3;
            }
        }
#pragma unroll
        for (int e = 0; e < 8; ++e) s2[hv * 8 + e][j] = silu_f(acc[e]);
    }
    __syncthreads();
    {
        float acc[8];
        float bias = b3[j];
#pragma unroll
        for (int e = 0; e < 8; ++e) acc[e] = bias;
        for (int k4 = 0; k4 < 32; ++k4) {
            float w0 = W3[(k4 * 4 + 0) * 128 + j];
            float w1 = W3[(k4 * 4 + 1) * 128 + j];
            float w2 = W3[(k4 * 4 + 2) * 128 + j];
            float w3 = W3[(k4 * 4 + 3) * 128 + j];
#pragma unroll
            for (int e = 0; e < 8; ++e) {
                const float4 v = *(const float4*)&s2[hv * 8 + e][k4 * 4];
                acc[e] += v.x * w0 + v.y * w1 + v.z * w2 + v.w * w3;
            }
        }
#pragma unroll
        for (int e = 0; e < 8; ++e) {
            size_t o = (size_t)(n0 + hv * 8 + e) * HDIM + j;
            h[o] = acc[e];
            hb[o] = f2bu(acc[e]);
        }
    }
}

// ---------------------------------------------------------------- MFMA edge kernel
// 128 edges x 128 ch per block, 4 waves. 3 chained GEMMs + coord dot + scatter.
// Layouts (HW-verified, 16x16x32 bf16): A[m=l16][k=quad*8+j], B[k=quad*8+j][n=l16],
// D[m=quad*4+r][n=l16].
__global__ __launch_bounds__(256) void edge_mfma_kernel(
    const unsigned short* __restrict__ hb, const float* __restrict__ pos,
    const void* __restrict__ ei, const int* __restrict__ flags,
    const unsigned short* __restrict__ w1t,   // [128][264]
    const unsigned short* __restrict__ w2t,   // [128][136]
    const unsigned short* __restrict__ c1t,   // [128][136]
    const float* __restrict__ eb1, const float* __restrict__ eb2,
    const float* __restrict__ cb1, const float* __restrict__ cw2,
    float* __restrict__ agg, float* __restrict__ cu)
{
    __shared__ __align__(16) unsigned short Abuf[128][40];   // A k-chunk (pad->2-way free)
    __shared__ __align__(16) unsigned short Bbuf[128][40];   // B k-chunk [n][k]
    __shared__ __align__(16) unsigned short Cbuf[128][136];  // h1 then m
    __shared__ float dsq[128], dpx[128], dpy[128], dpz[128], cwl[128];
    __shared__ int rowi[128], coli[128];

    const int tid = threadIdx.x;
    const int e0 = blockIdx.x * 128;

    if (tid < 128) {
        const int is64 = flags[1];
        int r = load_idx(ei, is64, e0 + tid);
        int c = load_idx(ei, is64, NEDGES + e0 + tid);
        rowi[tid] = r; coli[tid] = c;
        float dx = pos[r * 3 + 0] - pos[c * 3 + 0];
        float dy = pos[r * 3 + 1] - pos[c * 3 + 1];
        float dz = pos[r * 3 + 2] - pos[c * 3 + 2];
        dpx[tid] = dx; dpy[tid] = dy; dpz[tid] = dz;
        dsq[tid] = dx * dx + dy * dy + dz * dz;
    }
    __syncthreads();

    const int L = tid & 63, w = tid >> 6;
    const int quad = L >> 4, l16 = L & 15;
    const int m0 = w * 32;
    const int se = tid >> 1, sh = tid & 1;   // staging: row 0..127, half

    f32x4 acc[2][8];
    const f32x4 zero = {0.f, 0.f, 0.f, 0.f};

    // ---------- GEMM1: ef[128x256] @ W1[256x128]  (k=256 dist column as tail)
#pragma unroll
    for (int mt = 0; mt < 2; ++mt)
#pragma unroll
        for (int nt = 0; nt < 8; ++nt) acc[mt][nt] = zero;

    for (int kc = 0; kc < 8; ++kc) {
        const int k0 = kc * 32;
        const int node = (k0 < 128) ? rowi[se] : coli[se];
        const int koff = k0 & 127;
        const uint4* sa = (const uint4*)(hb + (size_t)node * HDIM + koff + sh * 16);
        uint4* da = (uint4*)&Abuf[se][sh * 16];
        da[0] = sa[0]; da[1] = sa[1];
        const uint4* sb = (const uint4*)(w1t + se * 264 + k0 + sh * 16);
        uint4* db = (uint4*)&Bbuf[se][sh * 16];
        db[0] = sb[0]; db[1] = sb[1];
        __syncthreads();
        bf16x8 a0 = *(const bf16x8*)&Abuf[m0 + l16][quad * 8];
        bf16x8 a1 = *(const bf16x8*)&Abuf[m0 + 16 + l16][quad * 8];
#pragma unroll
        for (int nt = 0; nt < 8; ++nt) {
            bf16x8 b = *(const bf16x8*)&Bbuf[nt * 16 + l16][quad * 8];
            acc[0][nt] = __builtin_amdgcn_mfma_f32_16x16x32_bf16(a0, b, acc[0][nt], 0, 0, 0);
            acc[1][nt] = __builtin_amdgcn_mfma_f32_16x16x32_bf16(a1, b, acc[1][nt], 0, 0, 0);
        }
        __syncthreads();
    }
    // dist tail (fp32) + bias + silu -> Cbuf = h1 (bf16)
#pragma unroll
    for (int nt = 0; nt < 8; ++nt) {
        const int n = nt * 16 + l16;
        const float wd = bu2f(w1t[n * 264 + 256]);
        const float bias = eb1[n];
#pragma unroll
        for (int mt = 0; mt < 2; ++mt)
#pragma unroll
            for (int r = 0; r < 4; ++r) {
                const int m = m0 + mt * 16 + quad * 4 + r;
                Cbuf[m][n] = f2bu(silu_f(acc[mt][nt][r] + bias + dsq[m] * wd));
            }
    }
    __syncthreads();

    // ---------- GEMM2: h1 @ W2 -> m
#pragma unroll
    for (int mt = 0; mt < 2; ++mt)
#pragma unroll
        for (int nt = 0; nt < 8; ++nt) acc[mt][nt] = zero;
    for (int kc = 0; kc < 4; ++kc) {
        const int k0 = kc * 32;
        const uint4* sb = (const uint4*)(w2t + se * 136 + k0 + sh * 16);
        uint4* db = (uint4*)&Bbuf[se][sh * 16];
        db[0] = sb[0]; db[1] = sb[1];
        __syncthreads();
        bf16x8 a0 = *(const bf16x8*)&Cbuf[m0 + l16][k0 + quad * 8];
        bf16x8 a1 = *(const bf16x8*)&Cbuf[m0 + 16 + l16][k0 + quad * 8];
#pragma unroll
        for (int nt = 0; nt < 8; ++nt) {
            bf16x8 b = *(const bf16x8*)&Bbuf[nt * 16 + l16][quad * 8];
            acc[0][nt] = __builtin_amdgcn_mfma_f32_16x16x32_bf16(a0, b, acc[0][nt], 0, 0, 0);
            acc[1][nt] = __builtin_amdgcn_mfma_f32_16x16x32_bf16(a1, b, acc[1][nt], 0, 0, 0);
        }
        __syncthreads();
    }
    // m = silu(acc + eb2) -> Cbuf (all reads of h1 completed at last barrier)
#pragma unroll
    for (int nt = 0; nt < 8; ++nt) {
        const int n = nt * 16 + l16;
        const float bias = eb2[n];
#pragma unroll
        for (int mt = 0; mt < 2; ++mt)
#pragma unroll
            for (int r = 0; r < 4; ++r) {
                const int m = m0 + mt * 16 + quad * 4 + r;
                Cbuf[m][n] = f2bu(silu_f(acc[mt][nt][r] + bias));
            }
    }
    __syncthreads();

    // ---------- GEMM3: m @ cW1 -> c1 (regs) ; cw = (silu(c1) . cW2)
#pragma unroll
    for (int mt = 0; mt < 2; ++mt)
#pragma unroll
        for (int nt = 0; nt < 8; ++nt) acc[mt][nt] = zero;
    for (int kc = 0; kc < 4; ++kc) {
        const int k0 = kc * 32;
        const uint4* sb = (const uint4*)(c1t + se * 136 + k0 + sh * 16);
        uint4* db = (uint4*)&Bbuf[se][sh * 16];
        db[0] = sb[0]; db[1] = sb[1];
        __syncthreads();
        bf16x8 a0 = *(const bf16x8*)&Cbuf[m0 + l16][k0 + quad * 8];
        bf16x8 a1 = *(const bf16x8*)&Cbuf[m0 + 16 + l16][k0 + quad * 8];
#pragma unroll
        for (int nt = 0; nt < 8; ++nt) {
            bf16x8 b = *(const bf16x8*)&Bbuf[nt * 16 + l16][quad * 8];
            acc[0][nt] = __builtin_amdgcn_mfma_f32_16x16x32_bf16(a0, b, acc[0][nt], 0, 0, 0);
            acc[1][nt] = __builtin_amdgcn_mfma_f32_16x16x32_bf16(a1, b, acc[1][nt], 0, 0, 0);
        }
        __syncthreads();
    }
    {
        float s[2][4] = {{0.f, 0.f, 0.f, 0.f}, {0.f, 0.f, 0.f, 0.f}};
#pragma unroll
        for (int nt = 0; nt < 8; ++nt) {
            const int n = nt * 16 + l16;
            const float bias = cb1[n];
            const float wv = cw2[n];
#pragma unroll
            for (int mt = 0; mt < 2; ++mt)
#pragma unroll
                for (int r = 0; r < 4; ++r)
                    s[mt][r] += silu_f(acc[mt][nt][r] + bias) * wv;
        }
#pragma unroll
        for (int mt = 0; mt < 2; ++mt)
#pragma unroll
            for (int r = 0; r < 4; ++r) {
                float v = s[mt][r];
                v += __shfl_xor(v, 1);
                v += __shfl_xor(v, 2);
                v += __shfl_xor(v, 4);
                v += __shfl_xor(v, 8);
                if (l16 == 0) cwl[m0 + mt * 16 + quad * 4 + r] = v;
            }
    }
    __syncthreads();

    // ---------- scatter: coord atomics + agg atomics (m is in Cbuf)
    if (tid < 128) {
        const int r = rowi[tid];
        const float cwv = cwl[tid];
        atomicAdd(&cu[r * 3 + 0], cwv * dpx[tid]);
        atomicAdd(&cu[r * 3 + 1], cwv * dpy[tid]);
        atomicAdd(&cu[r * 3 + 2], cwv * dpz[tid]);
    }
    const int j = tid & 127, hv = tid >> 7;
#pragma unroll 1
    for (int e = hv * 64; e < hv * 64 + 64; ++e)
        atomicAdd(&agg[(size_t)rowi[e] * HDIM + j], bu2f(Cbuf[e][j]));
}

// ---------------------------------------------------------------- node MLP + LN + pos
__global__ __launch_bounds__(256) void node_kernel(
    const float* __restrict__ h, const float* __restrict__ agg,
    const float* __restrict__ cu, const float* __restrict__ deg,
    const float* __restrict__ W1, const float* __restrict__ b1,
    const float* __restrict__ W2, const float* __restrict__ b2,
    const float* __restrict__ lg, const float* __restrict__ lb,
    float* __restrict__ h2, unsigned short* __restrict__ h2b,
    float* __restrict__ pos)
{
    __shared__ __align__(16) float xin[16][260];
    __shared__ __align__(16) float s1[16][132];
    __shared__ __align__(16) float xv[16][132];
    __shared__ float mus[16], rss[16];

    const int tid = threadIdx.x;
    const int n0 = blockIdx.x * 16;
    const int j = tid & 127, hv = tid >> 7;

    {
        const int off = hv * 128;
        for (int e = 0; e < 16; ++e) {
            int n = n0 + e;
            xin[e][off + j] = hv ? agg[(size_t)n * HDIM + j] : h[(size_t)n * HDIM + j];
        }
    }
    __syncthreads();

    float acc[8];
    {
        float bias = b1[j];
#pragma unroll
        for (int e = 0; e < 8; ++e) acc[e] = bias;
        for (int k4 = 0; k4 < 64; ++k4) {
            float w0 = W1[(k4 * 4 + 0) * 128 + j];
            float w1 = W1[(k4 * 4 + 1) * 128 + j];
            float w2 = W1[(k4 * 4 + 2) * 128 + j];
            float w3 = W1[(k4 * 4 + 3) * 128 + j];
#pragma unroll
            for (int e = 0; e < 8; ++e) {
                const float4 v = *(const float4*)&xin[hv * 8 + e][k4 * 4];
                acc[e] += v.x * w0 + v.y * w1 + v.z * w2 + v.w * w3;
            }
        }
#pragma unroll
        for (int e = 0; e < 8; ++e) s1[hv * 8 + e][j] = silu_f(acc[e]);
    }
    __syncthreads();
    {
        float bias = b2[j];
#pragma unroll
        for (int e = 0; e < 8; ++e) acc[e] = bias;
        for (int k4 = 0; k4 < 32; ++k4) {
            float w0 = W2[(k4 * 4 + 0) * 128 + j];
            float w1 = W2[(k4 * 4 + 1) * 128 + j];
            float w2 = W2[(k4 * 4 + 2) * 128 + j];
            float w3 = W2[(k4 * 4 + 3) * 128 + j];
#pragma unroll
            for (int e = 0; e < 8; ++e) {
                const float4 v = *(const float4*)&s1[hv * 8 + e][k4 * 4];
                acc[e] += v.x * w0 + v.y * w1 + v.z * w2 + v.w * w3;
            }
        }
#pragma unroll
        for (int e = 0; e < 8; ++e) {
            int ee = hv * 8 + e;
            xv[ee][j] = xin[ee][j] + acc[e];
        }
    }
    __syncthreads();

    if (tid < 16) {
        float s = 0.0f, ss = 0.0f;
#pragma unroll
        for (int k4 = 0; k4 < 32; ++k4) {
            const float4 v = *(const float4*)&xv[tid][k4 * 4];
            s  += v.x + v.y + v.z + v.w;
            ss += v.x * v.x + v.y * v.y + v.z * v.z + v.w * v.w;
        }
        float mu = s * (1.0f / 128.0f);
        float var = ss * (1.0f / 128.0f) - mu * mu;
        mus[tid] = mu;
        rss[tid] = rsqrtf(fmaxf(var, 0.0f) + 1e-5f);
        int n = n0 + tid;
        float inv = 1.0f / (deg[n] + 1e-6f);
        pos[n * 3 + 0] += cu[n * 3 + 0] * inv;
        pos[n * 3 + 1] += cu[n * 3 + 1] * inv;
        pos[n * 3 + 2] += cu[n * 3 + 2] * inv;
    }
    __syncthreads();
    {
        float gg = lg[j], bb = lb[j];
#pragma unroll
        for (int e = 0; e < 8; ++e) {
            int ee = hv * 8 + e;
            float val = (xv[ee][j] - mus[ee]) * rss[ee] * gg + bb;
            size_t o = (size_t)(n0 + ee) * HDIM + j;
            h2[o] = val;
            h2b[o] = f2bu(val);
        }
    }
}

// ---------------------------------------------------------------- launch
extern "C" void kernel_launch(void* const* d_in, const int* in_sizes, int n_in,
                              void* d_out, int out_size, void* d_ws, size_t ws_size,
                              hipStream_t stream) {
    const float* zF    = (const float*)d_in[0];
    const float* atomF = (const float*)d_in[1];
    const float* posI  = (const float*)d_in[2];
    const void*  ei    = d_in[3];
    const float* iW1 = (const float*)d_in[5];  const float* ib1 = (const float*)d_in[6];
    const float* iW2 = (const float*)d_in[7];  const float* ib2 = (const float*)d_in[8];
    const float* iW3 = (const float*)d_in[9];  const float* ib3 = (const float*)d_in[10];
    const float* eW1 = (const float*)d_in[11]; const float* eb1 = (const float*)d_in[12];
    const float* eW2 = (const float*)d_in[13]; const float* eb2 = (const float*)d_in[14];
    const float* nW1 = (const float*)d_in[15]; const float* nb1 = (const float*)d_in[16];
    const float* nW2 = (const float*)d_in[17]; const float* nb2 = (const float*)d_in[18];
    const float* cW1 = (const float*)d_in[19]; const float* cb1 = (const float*)d_in[20];
    const float* cW2 = (const float*)d_in[21];
    const float* lng = (const float*)d_in[22]; const float* lnb = (const float*)d_in[23];

    float* pos = (float*)d_out;   // fp32 output, verified R5

    float* ws = (float*)d_ws;
    int* flags = (int*)d_ws;
    size_t cur = 16;
    auto carve = [&](size_t n) { float* p = ws + cur; cur += n; return p; };
    float* deg  = carve(NNODES);
    float* cu   = carve((size_t)NNODES * 3);
    float* bufA = carve((size_t)NNODES * HDIM);          // h fp32
    float* bufB = carve((size_t)NNODES * HDIM);          // agg / h2 fp32 (aliased)
    unsigned short* hbA = (unsigned short*)carve((size_t)NNODES * HDIM / 2);
    unsigned short* hbB = (unsigned short*)carve((size_t)NNODES * HDIM / 2);
    unsigned short* w1t = (unsigned short*)carve((size_t)NLAYERS * 128 * 264 / 2);
    unsigned short* w2t = (unsigned short*)carve((size_t)NLAYERS * 128 * 136 / 2);
    unsigned short* c1t = (unsigned short*)carve((size_t)NLAYERS * 128 * 136 / 2);

    detect_kernel<<<1, 64, 0, stream>>>((const int*)ei, flags);
    pos_init_kernel<<<(NNODES * 3 + 255) / 256, 256, 0, stream>>>(posI, pos);
    hipMemsetAsync(deg, 0, NNODES * sizeof(float), stream);
    deg_kernel<<<NEDGES / 256, 256, 0, stream>>>(ei, flags, deg);
    prep_weights_kernel<<<1608, 256, 0, stream>>>(eW1, eW2, cW1, w1t, w2t, c1t);

    inj_kernel<<<NNODES / 16, 256, 0, stream>>>(atomF, zF, iW1, ib1, iW2, ib2, iW3, ib3,
                                                bufA, hbA);

    float* h = bufA;  unsigned short* hb = hbA;
    float* o = bufB;  unsigned short* ob = hbB;
    for (int l = 0; l < NLAYERS; ++l) {
        hipMemsetAsync(o, 0, (size_t)NNODES * HDIM * sizeof(float), stream);
        hipMemsetAsync(cu, 0, (size_t)NNODES * 3 * sizeof(float), stream);
        edge_mfma_kernel<<<NEDGES / 128, 256, 0, stream>>>(
            hb, pos, ei, flags,
            w1t + (size_t)l * 128 * 264,
            w2t + (size_t)l * 128 * 136,
            c1t + (size_t)l * 128 * 136,
            eb1 + l * 128, eb2 + l * 128, cb1 + l * 128, cW2 + l * 128,
            o, cu);
        node_kernel<<<NNODES / 16, 256, 0, stream>>>(
            h, o, cu, deg,
            nW1 + (size_t)l * 256 * 128, nb1 + l * 128,
            nW2 + (size_t)l * 128 * 128, nb2 + l * 128,
            lng + l * 128, lnb + l * 128, /*h2=*/o, /*h2b=*/ob, pos);
        float* t = h; h = o; o = t;
        unsigned short* tb = hb; hb = ob; ob = tb;
    }
}